// Round 11
// baseline (225.409 us; speedup 1.0000x reference)
//
#include <hip/hip_runtime.h>

// NCC forces, 192^3 fp32. Round 15 (2nd resubmit after GPU-acquisition
// timeouts in R13/R14): R8 skeleton + ZSEG 16 (single change).
// R12 post-mortem: 1-wave barrier-free blocks = 92us, occupancy STILL 33%
// -> convoy theory dead. Full ledger: LDS instrs X, conflicts X, capacity X,
// barriers X, residency X, HBM X. Constant across all variants: wall per
// block-iteration (~4900 cyc). Model: wall = K x iterations, K fixed.
// Only surviving lever: z-halo amortization. This round: ZSEG 12 -> 16
// on the byte-identical R8 structure: 21 iters / 16 slices vs 17/12
// -> per-voxel iteration cost x0.926. Predict dur 83.3 -> ~77us.
// (Also cleanly retests R6's confounded ZSEG-16 without role rotation.)

#define DD 192
#define HH 192
#define WW 192
#define NVOX (DD * HH * WW)
#define SLICE (HH * WW)
#define TS 16
#define RR 20            // staged rows (y: y0-2 .. y0+17)
#define RW 24            // staged row width (x: x0-4 .. x0+19)
#define ZSEG 16
#define NBX 12
#define NBY 12
#define NBZ 12
#define NBLK (NBX * NBY * NBZ)        // 1728
#define PER_XCD (NBLK / 8)            // 216

__global__ __launch_bounds__(256)
void ncc_forces_kernel(const float* __restrict__ mimg,
                       const float* __restrict__ fimg,
                       const int*   __restrict__ mmask,
                       const int*   __restrict__ fmask,
                       float* __restrict__ out)
{
    __shared__ float rawm[RR][RW];        // 1920 B (single slot)
    __shared__ float rawf[RR][RW];        // 1920 B
    __shared__ float xs[5][RR][20];       // 8000 B  [field][yrow][xo]
    __shared__ float Tf[4][RR][20];       // 6400 B  (m+f); col k <-> raw local k+2
    __shared__ float box[2][TS][5][20];   // 12800 B [pp][x][field][yout]
    // total 31040 B -> alloc 31232 B

    // XCD swizzle: XCD k gets 216 consecutive logical blocks
    const int b  = blockIdx.x;
    const int L  = (b & 7) * PER_XCD + (b >> 3);
    const int bz = L / (NBX * NBY);
    const int r_ = L - bz * (NBX * NBY);
    const int by = r_ / NBX;
    const int bx = r_ - by * NBX;

    const int tid = threadIdx.x;
    const int tx = tid & 15, ty = tid >> 4;
    const int x0 = bx * TS, y0 = by * TS, z0 = bz * ZSEG;

    // ---- staging roles: 240 lanes = 2 images x 20 rows x 6 quads ----
    const int  simg   = tid / 120;            // 0,1 stager; 2 idle
    const bool stager = (simg < 2);
    const int  st     = tid - simg * 120;
    const int  srow   = st / 6;
    const int  squad  = st - srow * 6;
    const int  sgy    = y0 - 2 + srow;
    const int  sgx    = x0 - 4 + 4 * squad;   // quads all-in or all-out (x0%16==0)
    const bool sin_   = (sgy >= 0) && (sgy < HH) && (sgx >= 0) && (sgx <= WW - 4);
    const float* sptr = (simg == 1) ? fimg : mimg;
    float* sldsb = (simg == 1) ? &rawf[0][0] : &rawm[0][0];
    const int  sloff  = srow * RW + 4 * squad;

    float4 pref = make_float4(0, 0, 0, 0);
    auto prefetch = [&](int zz) {
        pref = make_float4(0, 0, 0, 0);
        if (stager && sin_ && zz >= 0 && zz < DD)
            pref = *(const float4*)(sptr + ((size_t)zz * HH + sgy) * WW + sgx);
    };

    // per-thread rings
    float ring[5][5];
#pragma unroll
    for (int s = 0; s < 5; ++s)
#pragma unroll
        for (int f = 0; f < 5; ++f) ring[s][f] = 0.f;
    float cm[5] = {0, 0, 0, 0, 0}, cf[5] = {0, 0, 0, 0, 0};

    const int gx = x0 + tx, gy = y0 + ty;
    const int vbase = (z0 * HH + gy) * WW + gx;   // voxel index at z=z0
    int umN = 0, ufN = 0;                          // masks prefetched 1 iter ahead

    prefetch(z0 - 2);

    for (int n = 0; n <= ZSEG + 4; ++n) {
        const int zc = z0 - 2 + n;           // slice committed this iter
        const int z  = zc - 3;               // slice emitted this iter
        const bool emitv = (n >= 5);

        // ---- commit staged slice zc; issue loads for zc+1 ----
        // WAR vs iter-(n-1)'s raw reads is fenced by barrier B of iter n-1.
        if (stager) *(float4*)(sldsb + sloff) = pref;
        prefetch(zc + 1);

        const int um = umN, uf = ufN;        // masks for THIS iter's emit
        if (n >= 4 && n < ZSEG + 4) {        // prefetch for iter n+1
            const int vn = vbase + (n - 4) * SLICE;
            umN = __builtin_nontemporal_load(mmask + vn);
            ufN = __builtin_nontemporal_load(fmask + vn);
        }

        __syncthreads();   // A: raw ready; box[(n-1)&1] (y of n-1) ready

        // ---- x-phase: 80 chunk-of-4 tasks; also emits T = m+f row ----
        if (tid < 80) {
            const int yy = tid >> 2;          // 0..19
            const int t4 = (tid & 3) * 4;     // 0,4,8,12
            const float4 A0 = *(const float4*)&rawm[yy][t4];
            const float4 A1 = *(const float4*)&rawm[yy][t4 + 4];
            const float2 A2 = *(const float2*)&rawm[yy][t4 + 8];
            const float4 B0 = *(const float4*)&rawf[yy][t4];
            const float4 B1 = *(const float4*)&rawf[yy][t4 + 4];
            const float2 B2 = *(const float2*)&rawf[yy][t4 + 8];
            const float a[10]  = {A0.x, A0.y, A0.z, A0.w, A1.x, A1.y, A1.z, A1.w, A2.x, A2.y};
            const float bb[10] = {B0.x, B0.y, B0.z, B0.w, B1.x, B1.y, B1.z, B1.w, B2.x, B2.y};
            float p[10], s, w0, w1, w2, w3;
#pragma unroll
            for (int f = 0; f < 5; ++f) {
#pragma unroll
                for (int i = 2; i < 10; ++i) {
                    p[i] = (f == 0) ? a[i] : (f == 1) ? bb[i] :
                           (f == 2) ? a[i] * a[i] : (f == 3) ? bb[i] * bb[i] : a[i] * bb[i];
                }
                s = p[2] + p[3] + p[4] + p[5] + p[6]; w0 = s;
                s += p[7] - p[2]; w1 = s;
                s += p[8] - p[3]; w2 = s;
                s += p[9] - p[4]; w3 = s;
                *(float4*)&xs[f][yy][t4] = make_float4(w0, w1, w2, w3);
            }
            // T[yy][k] = (m+f) at raw local k+2  (k = 0..19)
            const int tw = n & 3;
            *(float4*)&Tf[tw][yy][t4] =
                make_float4(a[2] + bb[2], a[3] + bb[3], a[4] + bb[4], a[5] + bb[5]);
            if (t4 == 12)
                *(float4*)&Tf[tw][yy][16] =
                    make_float4(a[6] + bb[6], a[7] + bb[7], a[8] + bb[8], a[9] + bb[9]);
        }

        // ---- centers: fresh slice zc -> register ring ----
        {
            const float ncm = rawm[ty + 2][tx + 4];
            const float ncf = rawf[ty + 2][tx + 4];
#pragma unroll
            for (int s2 = 4; s2 > 0; --s2) { cm[s2] = cm[s2 - 1]; cf[s2] = cf[s2 - 1]; }
            cm[0] = ncm; cf[0] = ncf;
        }
        // 2D sums of slice zc-1 (y-phase of iter n-1) -> ring
        if (n >= 1) {
            const int pp = (n - 1) & 1;
            const float* bq = &box[pp][tx][0][ty];    // f-stride 20 dwords -> read2 merge
            const float s0 = bq[0], s1 = bq[20], s2v = bq[40], s3 = bq[60], s4 = bq[80];
#pragma unroll
            for (int s = 0; s < 4; ++s)
#pragma unroll
                for (int f = 0; f < 5; ++f) ring[s][f] = ring[s + 1][f];
            ring[4][0] = s0; ring[4][1] = s1; ring[4][2] = s2v; ring[4][3] = s3; ring[4][4] = s4;
        }

        if (emitv) {
            float sum_m = 0.f, sum_f = 0.f, sum_mm = 0.f, sum_ff = 0.f, sum_mf = 0.f;
#pragma unroll
            for (int s = 0; s < 5; ++s) {
                sum_m  += ring[s][0];
                sum_f  += ring[s][1];
                sum_mm += ring[s][2];
                sum_ff += ring[s][3];
                sum_mf += ring[s][4];
            }
            const int vidx = vbase + (n - 5) * SLICE;
            const int tsl = (n + 1) & 3;       // T slot of slice z (written iter n-3)
            const int cy = ty + 2;
            const float mc = cm[3];            // center at z
            const float fc = cf[3];
            const float Tc = mc + fc;

            // gradient sums via T field: 2 read2-mergeable pairs
            const float* tp = &Tf[tsl][cy][tx + 1];       // {gx-1, gx+1}: offs 0,2
            const float Txm = tp[0], Txp = tp[2];
            const float* tq = &Tf[tsl][cy - 1][tx + 2];   // {gy-1, gy+1}: offs 0,40
            const float Tym = tq[0], Typ = tq[40];

            float gsx, gsy, gsz;
            if (gx == 0)          gsx = Txp - Tc;
            else if (gx == WW-1)  gsx = Tc - Txm;
            else                  gsx = 0.5f * (Txp - Txm);
            if (gy == 0)          gsy = Typ - Tc;
            else if (gy == HH-1)  gsy = Tc - Tym;
            else                  gsy = 0.5f * (Typ - Tym);
            const float Tzm = cm[4] + cf[4], Tzp = cm[2] + cf[2];
            if (z == 0)           gsz = Tzp - Tc;
            else if (z == DD-1)   gsz = Tc - Tzm;
            else                  gsz = 0.5f * (Tzp - Tzm);

            const float u = ((um != 0) || (uf != 0)) ? 1.0f : 0.0f;

            const float npix = 125.0f;
            const float inv_npix = 1.0f / 125.0f;
            const float mean_m = sum_m * inv_npix;
            const float mean_f = sum_f * inv_npix;
            const float var_m = sum_mm - 2.0f * mean_m * sum_m + npix * mean_m * mean_m;
            const float var_f = sum_ff - 2.0f * mean_f * sum_f + npix * mean_f * mean_f;
            const float var_mf = var_m * var_f;
            const float cross = sum_mf - mean_f * sum_m - mean_m * sum_f + npix * mean_m * mean_f;
            const float mmc = mc - mean_m;
            const float fmc = fc - mean_f;
            const bool ok = (var_mf > 1e-5f) && (var_f > 1e-5f) && (fmc != 0.0f) && (mmc != 0.0f);
            float factor = 0.0f;
            if (ok) factor = 2.0f * cross / var_mf * (mmc - cross * fmc / var_f);

            const float nf = -factor * 0.5f * u;
            out[vidx]            = nf * gsz;   // ch 0: d/dD
            out[NVOX + vidx]     = nf * gsy;   // ch 1: d/dH
            out[2 * NVOX + vidx] = nf * gsx;   // ch 2: d/dW
        }

        __syncthreads();   // B: xs/Tf ready; emit/x reads of raw done

        // ---- y-phase: 160 chunk-of-8 sliding tasks -> box[n&1] ----
        if (tid < 160) {
            const int x  = tid & 15;
            const int c8 = ((tid >> 4) & 1) * 8;   // 0 or 8
            const int f  = tid >> 5;               // 0..4
            const float* xp = &xs[f][c8][x];       // stride 20 dwords -> read2 merge
            float v[12];
#pragma unroll
            for (int j = 0; j < 12; ++j) v[j] = xp[20 * j];
            float o[8];
            float s = v[0] + v[1] + v[2] + v[3] + v[4];
            o[0] = s;
#pragma unroll
            for (int j = 1; j < 8; ++j) { s += v[j + 4] - v[j - 1]; o[j] = s; }
            float* bp = &box[n & 1][x][f][c8];
            *(float4*)bp       = make_float4(o[0], o[1], o[2], o[3]);
            *(float4*)(bp + 4) = make_float4(o[4], o[5], o[6], o[7]);
        }
        // no trailing barrier:
        //  - commit(n+1) writes raw after B(n); iter-n raw reads were pre-B.
        //  - next x-phase (writes xs/Tf[(n+1)&3]) is fenced by next barrier A;
        //    Tf[(n+1)&3] was last read at emit(n) before B(n).
        //  - box[n&1] is read at emit(n+1) after A(n+1), rewritten at y(n+2).
    }
}

extern "C" void kernel_launch(void* const* d_in, const int* in_sizes, int n_in,
                              void* d_out, int out_size, void* d_ws, size_t ws_size,
                              hipStream_t stream)
{
    const float* mimg  = (const float*)d_in[0];
    const float* fimg  = (const float*)d_in[1];
    const int*   mmask = (const int*)d_in[2];
    const int*   fmask = (const int*)d_in[3];
    float* out = (float*)d_out;

    dim3 grid(NBLK, 1, 1);   // 1728 blocks
    dim3 block(256, 1, 1);
    hipLaunchKernelGGL(ncc_forces_kernel, grid, block, 0, stream,
                       mimg, fimg, mmask, fmask, out);
}